// Round 8
// baseline (279.127 us; speedup 1.0000x reference)
//
#include <hip/hip_runtime.h>
#include <hip/hip_bf16.h>
#include <stdint.h>

typedef __bf16 bf16;
typedef __bf16 bf16x4 __attribute__((ext_vector_type(4)));
typedef __bf16 bf16x8 __attribute__((ext_vector_type(8)));
typedef float f32x4 __attribute__((ext_vector_type(4)));

#define MFMA(a, b, c) __builtin_amdgcn_mfma_f32_16x16x32_bf16(a, b, c, 0, 0, 0)

// ---- prep: weight transposes fp32 [K,N] -> bf16 [N,K] ----
__device__ inline void tp(const float* W, bf16* WT, int id, int shiftK, int N) {
  int K = 1 << shiftK;
  int n = id >> shiftK;
  int k = id & (K - 1);
  WT[id] = (bf16)W[(size_t)k * N + n];
}

__global__ __launch_bounds__(256) void prep_all(
    const float* __restrict__ W1, const float* __restrict__ W2,
    bf16* __restrict__ W1T, bf16* __restrict__ W2T,
    const float* __restrict__ Wpre, const float* __restrict__ Wloc,
    const float* __restrict__ Wgcn, const float* __restrict__ Wpost,
    bf16* __restrict__ WpreLocT, bf16* __restrict__ Wg0T, bf16* __restrict__ Wg1T,
    bf16* __restrict__ WpostT) {
  __shared__ bf16 tile[64 * 68];
  int blk = blockIdx.x;
  int tid = threadIdx.x;
  if (blk < 128) {                       // tiled transpose W1/W2 (512x512 each)
    const float* W = (blk < 64) ? W1 : W2;
    bf16* WT = (blk < 64) ? W1T : W2T;
    int t = blk & 63;
    int tk0 = (t >> 3) * 64, tn0 = (t & 7) * 64;
#pragma unroll
    for (int p = 0; p < 4; p++) {
      int kr = p * 16 + (tid >> 4), nc = (tid & 15) * 4;
      float4 f = *(const float4*)(W + (size_t)(tk0 + kr) * 512 + tn0 + nc);
      bf16x4 v; v[0] = (bf16)f.x; v[1] = (bf16)f.y; v[2] = (bf16)f.z; v[3] = (bf16)f.w;
      *(bf16x4*)&tile[kr * 68 + nc] = v;
    }
    __syncthreads();
#pragma unroll
    for (int p = 0; p < 4; p++) {
      int nr = p * 16 + (tid >> 4), kc = (tid & 15) * 4;
      bf16x4 v;
#pragma unroll
      for (int i = 0; i < 4; i++) v[i] = tile[(kc + i) * 68 + nr];
      *(bf16x4*)(WT + (size_t)(tn0 + nr) * 512 + tk0 + kc) = v;
    }
    return;
  }
  blk -= 128;
  // small transposes (448 blocks)
  int id = blk * 256 + tid;
  if (id < 16384) { tp(Wpre, WpreLocT, id, 7, 128); return; } id -= 16384;
  if (id < 32768) { tp(Wloc, WpreLocT + 16384, id, 7, 256); return; } id -= 32768;
  if (id < 16384) { tp(Wgcn, Wg0T, id, 7, 128); return; } id -= 16384;
  if (id < 16384) { tp(Wgcn + 16384, Wg1T, id, 7, 128); return; } id -= 16384;
  tp(Wpost, WpostT, id, 7, 256);
}

// ---- megakernel: whole net, one block per 64 rows (4 samples) ----
// Row-local fusion: pre+pool -> gcn chain -> [g|loc]@W1 -> @W2 -> q-head.
// All k-loops are BARRIER-FREE: B-frags read direct from global (L2-resident
// weights), A from LDS (obs) or global (loc/z1, same-block L2). Barriers only
// at stage boundaries. No atomics: each block owns its 64 output rows.
__global__ __launch_bounds__(256, 2) void mega(
    const float* __restrict__ obs,
    const bf16* __restrict__ WpreLocT, const float* __restrict__ b_pre,
    const float* __restrict__ b_loc,
    const bf16* __restrict__ Wg0T, const bf16* __restrict__ Wg1T,
    const bf16* __restrict__ WpostT, const float* __restrict__ b_gcn,
    const float* __restrict__ b_post,
    const bf16* __restrict__ W1T, const float* __restrict__ b1,
    const bf16* __restrict__ W2T, const float* __restrict__ b2,
    const float* __restrict__ W3, const float* __restrict__ b3,
    bf16* __restrict__ loc, bf16* __restrict__ z1, float* __restrict__ out) {
  __shared__ bf16 R0[64 * 136];    // stA (obs tile) in S1; z2 chunk in S4
  __shared__ bf16 xbS[16 * 136];   // xbar (rows 0..3 real, 4..15 zeroed)
  __shared__ bf16 x2S[16 * 136];   // gcn ping-pong
  __shared__ bf16 gS[16 * 256];    // g (rows 0..3 real)

  const int tid = threadIdx.x;
  const int lane = tid & 63, wave = tid >> 6;
  const int wm = (wave >> 1) * 32, wn = (wave & 1) * 64;
  const int lm = lane & 15, quad = lane >> 4;
  const int r0 = blockIdx.x * 64;

  // ---- S1a: stage obs fp32 -> bf16 into R0 [64][136] (pad: 2-way banks) ----
#pragma unroll
  for (int it = 0; it < 4; ++it) {
    int idx = it * 256 + tid;        // 1024 chunks of 8
    int row = idx >> 4, c = idx & 15;
    const float* s = obs + (size_t)(r0 + row) * 128 + c * 8;
    float4 f0 = *(const float4*)s, f1 = *(const float4*)(s + 4);
    bf16x8 v;
    v[0] = (bf16)f0.x; v[1] = (bf16)f0.y; v[2] = (bf16)f0.z; v[3] = (bf16)f0.w;
    v[4] = (bf16)f1.x; v[5] = (bf16)f1.y; v[6] = (bf16)f1.z; v[7] = (bf16)f1.w;
    *(bf16x8*)&R0[row * 136 + c * 8] = v;
  }
  if (tid < 192) {                   // zero xbS rows 4..15 (finite garbage guard)
    bf16x8 z = {};
    *(bf16x8*)&xbS[(4 + (tid >> 4)) * 136 + (tid & 15) * 8] = z;
  }
  __syncthreads();

  // ---- S1b: K1 n-tiles: nt=0 pre->pool(xbS); nt=1,2 loc -> global ----
  for (int nt = 0; nt < 3; ++nt) {
    f32x4 acc[2][4] = {};
#pragma unroll
    for (int ku = 0; ku < 4; ++ku) {
      bf16x8 a[2], b[4];
#pragma unroll
      for (int i = 0; i < 2; ++i)
        a[i] = *(const bf16x8*)&R0[(wm + lm + i * 16) * 136 + (ku * 4 + quad) * 8];
#pragma unroll
      for (int j = 0; j < 4; ++j)
        b[j] = *(const bf16x8*)&WpreLocT[(size_t)(nt * 128 + wn + j * 16 + lm) * 128 + ku * 32 + quad * 8];
#pragma unroll
      for (int i = 0; i < 2; ++i)
#pragma unroll
        for (int j = 0; j < 4; ++j)
          acc[i][j] = MFMA(a[i], b[j], acc[i][j]);
    }
    if (nt == 0) {                   // pool over 16 agents -> xbS rows 0..3
#pragma unroll
      for (int i = 0; i < 2; ++i) {
        int sl = (wave >> 1) * 2 + i;
#pragma unroll
        for (int j = 0; j < 4; ++j) {
          int col = wn + j * 16 + lm;
          float bb = b_pre[col];
          float v = 0.f;
#pragma unroll
          for (int r = 0; r < 4; ++r) v += fmaxf(acc[i][j][r] + bb, 0.f);
          v += __shfl_xor(v, 16);
          v += __shfl_xor(v, 32);
          if (quad == 0) xbS[sl * 136 + col] = (bf16)(v * 0.0625f);
        }
      }
    } else {                         // loc -> global (C-layout stores)
#pragma unroll
      for (int i = 0; i < 2; ++i)
#pragma unroll
        for (int j = 0; j < 4; ++j) {
          int col = wn + j * 16 + lm;
          float bb = b_loc[(nt - 1) * 128 + col];
#pragma unroll
          for (int r = 0; r < 4; ++r) {
            int row = r0 + wm + i * 16 + quad * 4 + r;
            loc[(size_t)row * 256 + (nt - 1) * 128 + col] = (bf16)fmaxf(acc[i][j][r] + bb, 0.f);
          }
        }
    }
  }
  __syncthreads();

  // ---- S2: collapsed GCN chain (M=16 frags, rows 0..3 real) ----
  {  // l0: xbS -> x2S
    f32x4 a2[2] = {};
#pragma unroll
    for (int ku = 0; ku < 4; ++ku) {
      bf16x8 a = *(const bf16x8*)&xbS[lm * 136 + (ku * 4 + quad) * 8];
#pragma unroll
      for (int jn = 0; jn < 2; ++jn) {
        int col = (wave * 2 + jn) * 16 + lm;
        bf16x8 b = *(const bf16x8*)&Wg0T[(size_t)col * 128 + ku * 32 + quad * 8];
        a2[jn] = MFMA(a, b, a2[jn]);
      }
    }
    __syncthreads();
#pragma unroll
    for (int jn = 0; jn < 2; ++jn) {
      int col = (wave * 2 + jn) * 16 + lm;
      float bb = b_gcn[col];
#pragma unroll
      for (int r = 0; r < 4; ++r)
        x2S[(quad * 4 + r) * 136 + col] = (bf16)fmaxf(a2[jn][r] + bb, 0.f);
    }
  }
  __syncthreads();
  {  // l1: x2S -> xbS
    f32x4 a2[2] = {};
#pragma unroll
    for (int ku = 0; ku < 4; ++ku) {
      bf16x8 a = *(const bf16x8*)&x2S[lm * 136 + (ku * 4 + quad) * 8];
#pragma unroll
      for (int jn = 0; jn < 2; ++jn) {
        int col = (wave * 2 + jn) * 16 + lm;
        bf16x8 b = *(const bf16x8*)&Wg1T[(size_t)col * 128 + ku * 32 + quad * 8];
        a2[jn] = MFMA(a, b, a2[jn]);
      }
    }
    __syncthreads();
#pragma unroll
    for (int jn = 0; jn < 2; ++jn) {
      int col = (wave * 2 + jn) * 16 + lm;
      float bb = b_gcn[128 + col];
#pragma unroll
      for (int r = 0; r < 4; ++r)
        xbS[(quad * 4 + r) * 136 + col] = (bf16)fmaxf(a2[jn][r] + bb, 0.f);
    }
  }
  __syncthreads();
  {  // l2: xbS -> gS (N=256)
    f32x4 a3[4] = {};
#pragma unroll
    for (int ku = 0; ku < 4; ++ku) {
      bf16x8 a = *(const bf16x8*)&xbS[lm * 136 + (ku * 4 + quad) * 8];
#pragma unroll
      for (int jn = 0; jn < 4; ++jn) {
        int col = (wave * 4 + jn) * 16 + lm;
        bf16x8 b = *(const bf16x8*)&WpostT[(size_t)col * 128 + ku * 32 + quad * 8];
        a3[jn] = MFMA(a, b, a3[jn]);
      }
    }
    __syncthreads();
#pragma unroll
    for (int jn = 0; jn < 4; ++jn) {
      int col = (wave * 4 + jn) * 16 + lm;
      float bb = b_post[col];
#pragma unroll
      for (int r = 0; r < 4; ++r)
        gS[(quad * 4 + r) * 256 + col] = (bf16)fmaxf(a3[jn][r] + bb, 0.f);
    }
  }
  __syncthreads();

  // ---- S3: z1 = relu([g|loc] @ W1T + b1), barrier-free k-loop ----
  for (int jj = 0; jj < 4; ++jj) {
    f32x4 acc[2][4] = {};
#pragma unroll 4
    for (int ku = 0; ku < 8; ++ku) {         // k < 256: A = g (LDS broadcast)
      bf16x8 a[2], b[4];
#pragma unroll
      for (int i = 0; i < 2; ++i) {
        int sl = (wave >> 1) * 2 + i;
        a[i] = *(const bf16x8*)&gS[sl * 256 + ku * 32 + quad * 8];
      }
#pragma unroll
      for (int j = 0; j < 4; ++j)
        b[j] = *(const bf16x8*)&W1T[(size_t)(jj * 128 + wn + j * 16 + lm) * 512 + ku * 32 + quad * 8];
#pragma unroll
      for (int i = 0; i < 2; ++i)
#pragma unroll
        for (int j = 0; j < 4; ++j)
          acc[i][j] = MFMA(a[i], b[j], acc[i][j]);
    }
#pragma unroll 4
    for (int ku = 8; ku < 16; ++ku) {        // k >= 256: A = loc (global, L2)
      bf16x8 a[2], b[4];
#pragma unroll
      for (int i = 0; i < 2; ++i)
        a[i] = *(const bf16x8*)&loc[(size_t)(r0 + wm + lm + i * 16) * 256 + (ku - 8) * 32 + quad * 8];
#pragma unroll
      for (int j = 0; j < 4; ++j)
        b[j] = *(const bf16x8*)&W1T[(size_t)(jj * 128 + wn + j * 16 + lm) * 512 + ku * 32 + quad * 8];
#pragma unroll
      for (int i = 0; i < 2; ++i)
#pragma unroll
        for (int j = 0; j < 4; ++j)
          acc[i][j] = MFMA(a[i], b[j], acc[i][j]);
    }
#pragma unroll
    for (int i = 0; i < 2; ++i)
#pragma unroll
      for (int j = 0; j < 4; ++j) {
        int col = jj * 128 + wn + j * 16 + lm;
        float bb = b1[col];
#pragma unroll
        for (int r = 0; r < 4; ++r) {
          int row = r0 + wm + i * 16 + quad * 4 + r;
          z1[(size_t)row * 512 + col] = (bf16)fmaxf(acc[i][j][r] + bb, 0.f);
        }
      }
  }
  __syncthreads();   // drain z1 stores before reads (same block, same XCD L2)

  // ---- S4: z2 = relu(z1 @ W2T + b2) fused with q-head ----
  float qacc[16];
#pragma unroll
  for (int rr = 0; rr < 16; ++rr) qacc[rr] = 0.f;
  const int qn = lane & 7, kg = lane >> 3;

  for (int jj = 0; jj < 4; ++jj) {
    f32x4 acc[2][4] = {};
#pragma unroll 4
    for (int ku = 0; ku < 16; ++ku) {
      bf16x8 a[2], b[4];
#pragma unroll
      for (int i = 0; i < 2; ++i)
        a[i] = *(const bf16x8*)&z1[(size_t)(r0 + wm + lm + i * 16) * 512 + ku * 32 + quad * 8];
#pragma unroll
      for (int j = 0; j < 4; ++j)
        b[j] = *(const bf16x8*)&W2T[(size_t)(jj * 128 + wn + j * 16 + lm) * 512 + ku * 32 + quad * 8];
#pragma unroll
      for (int i = 0; i < 2; ++i)
#pragma unroll
        for (int j = 0; j < 4; ++j)
          acc[i][j] = MFMA(a[i], b[j], acc[i][j]);
    }
    __syncthreads();                  // R0 chunk reuse across jj
#pragma unroll
    for (int i = 0; i < 2; ++i)
#pragma unroll
      for (int j = 0; j < 4; ++j) {
        int col = wn + j * 16 + lm;
        float bb = b2[jj * 128 + col];
#pragma unroll
        for (int r = 0; r < 4; ++r) {
          int row = wm + i * 16 + quad * 4 + r;
          R0[row * 136 + col] = (bf16)fmaxf(acc[i][j][r] + bb, 0.f);
        }
      }
    __syncthreads();
    float w3r[16];
#pragma unroll
    for (int i = 0; i < 16; ++i) w3r[i] = W3[(size_t)(jj * 128 + kg * 16 + i) * 8 + qn];
    for (int rr = 0; rr < 16; ++rr) {
      const bf16* zr = &R0[(wave * 16 + rr) * 136 + kg * 16];
      bf16x8 z0 = *(const bf16x8*)zr, z1v = *(const bf16x8*)(zr + 8);
      float v = 0.f;
#pragma unroll
      for (int i = 0; i < 8; ++i) v += (float)z0[i] * w3r[i];
#pragma unroll
      for (int i = 0; i < 8; ++i) v += (float)z1v[i] * w3r[8 + i];
      v += __shfl_down(v, 32);
      v += __shfl_down(v, 16);
      v += __shfl_down(v, 8);
      qacc[rr] += v;                  // lanes<8 hold the true sum
    }
  }
  if (lane < 8) {
    float bb = b3[qn];
#pragma unroll
    for (int rr = 0; rr < 16; ++rr)
      out[(size_t)(r0 + wave * 16 + rr) * 8 + qn] = qacc[rr] + bb;
  }
}

extern "C" void kernel_launch(void* const* d_in, const int* in_sizes, int n_in,
                              void* d_out, int out_size, void* d_ws, size_t ws_size,
                              hipStream_t stream) {
  const float* obs    = (const float*)d_in[0];
  const float* W_pre  = (const float*)d_in[1];
  const float* b_pre  = (const float*)d_in[2];
  const float* W_gcn  = (const float*)d_in[3];
  const float* b_gcn  = (const float*)d_in[4];
  const float* W_post = (const float*)d_in[5];
  const float* b_post = (const float*)d_in[6];
  const float* W_loc  = (const float*)d_in[7];
  const float* b_loc  = (const float*)d_in[8];
  const float* W1     = (const float*)d_in[9];
  const float* b1     = (const float*)d_in[10];
  const float* W2     = (const float*)d_in[11];
  const float* b2     = (const float*)d_in[12];
  const float* W3     = (const float*)d_in[13];
  const float* b3     = (const float*)d_in[14];
  float* out = (float*)d_out;

  char* p = (char*)d_ws;
  auto alloc = [&](size_t bytes) { char* r = p; p += (bytes + 255) & ~(size_t)255; return r; };
  bf16* WpreLocT = (bf16*)alloc(384 * 128 * 2);
  bf16* Wg0T   = (bf16*)alloc(128 * 128 * 2);
  bf16* Wg1T   = (bf16*)alloc(128 * 128 * 2);
  bf16* WpostT = (bf16*)alloc(256 * 128 * 2);
  bf16* W1T    = (bf16*)alloc(512 * 512 * 2);
  bf16* W2T    = (bf16*)alloc(512 * 512 * 2);
  bf16* locB   = (bf16*)alloc((size_t)32768 * 256 * 2);
  bf16* z1B    = (bf16*)alloc((size_t)32768 * 512 * 2);

  prep_all<<<576, 256, 0, stream>>>(W1, W2, W1T, W2T,
                                    W_pre, W_loc, W_gcn, W_post,
                                    WpreLocT, Wg0T, Wg1T, WpostT);
  mega<<<512, 256, 0, stream>>>(obs, WpreLocT, b_pre, b_loc,
                                Wg0T, Wg1T, WpostT, b_gcn, b_post,
                                W1T, b1, W2T, b2, W3, b3,
                                locB, z1B, out);
}

// Round 9
// 169.277 us; speedup vs baseline: 1.6489x; 1.6489x over previous
//
#include <hip/hip_runtime.h>
#include <hip/hip_bf16.h>
#include <stdint.h>

typedef __bf16 bf16;
typedef __bf16 bf16x4 __attribute__((ext_vector_type(4)));
typedef __bf16 bf16x8 __attribute__((ext_vector_type(8)));
typedef float f32x4 __attribute__((ext_vector_type(4)));

#define MFMA(a, b, c) __builtin_amdgcn_mfma_f32_16x16x32_bf16(a, b, c, 0, 0, 0)
#define GL(p) ((const __attribute__((address_space(1))) void*)(p))
#define SH(p) ((__attribute__((address_space(3))) void*)(p))

// ---- prep: W transposes (bf16), bias concat, zero d_out ----
__device__ inline void tp(const float* W, bf16* WT, int id, int shiftK, int N) {
  int K = 1 << shiftK;
  int n = id >> shiftK;
  int k = id & (K - 1);
  WT[id] = (bf16)W[(size_t)k * N + n];
}

__global__ __launch_bounds__(256) void prep_all(
    const float* __restrict__ W1, const float* __restrict__ W2,
    bf16* __restrict__ W1T, bf16* __restrict__ W2T,
    const float* __restrict__ Wpre, const float* __restrict__ Wloc,
    const float* __restrict__ Wgcn, const float* __restrict__ Wpost,
    bf16* __restrict__ WpreLocT, bf16* __restrict__ Wg0T, bf16* __restrict__ Wg1T,
    bf16* __restrict__ WpostT,
    const float* __restrict__ bpre, const float* __restrict__ bloc,
    float* __restrict__ biasPL, float* __restrict__ outq) {
  __shared__ bf16 tile[64 * 68];
  int blk = blockIdx.x;
  int tid = threadIdx.x;
  if (blk < 128) {                       // tiled transpose W1/W2 (512x512 each)
    const float* W = (blk < 64) ? W1 : W2;
    bf16* WT = (blk < 64) ? W1T : W2T;
    int t = blk & 63;
    int tk0 = (t >> 3) * 64, tn0 = (t & 7) * 64;
#pragma unroll
    for (int p = 0; p < 4; p++) {
      int kr = p * 16 + (tid >> 4), nc = (tid & 15) * 4;
      float4 f = *(const float4*)(W + (size_t)(tk0 + kr) * 512 + tn0 + nc);
      bf16x4 v; v[0] = (bf16)f.x; v[1] = (bf16)f.y; v[2] = (bf16)f.z; v[3] = (bf16)f.w;
      *(bf16x4*)&tile[kr * 68 + nc] = v;
    }
    __syncthreads();
#pragma unroll
    for (int p = 0; p < 4; p++) {
      int nr = p * 16 + (tid >> 4), kc = (tid & 15) * 4;
      bf16x4 v;
#pragma unroll
      for (int i = 0; i < 4; i++) v[i] = tile[(kc + i) * 68 + nr];
      *(bf16x4*)(WT + (size_t)(tn0 + nr) * 512 + tk0 + kc) = v;
    }
    return;
  }
  blk -= 128;
  if (blk < 448) {                       // small transposes
    int id = blk * 256 + tid;
    if (id < 16384) { tp(Wpre, WpreLocT, id, 7, 128); return; } id -= 16384;
    if (id < 32768) { tp(Wloc, WpreLocT + 16384, id, 7, 256); return; } id -= 32768;
    if (id < 16384) { tp(Wgcn, Wg0T, id, 7, 128); return; } id -= 16384;
    if (id < 16384) { tp(Wgcn + 16384, Wg1T, id, 7, 128); return; } id -= 16384;
    tp(Wpost, WpostT, id, 7, 256);
    return;
  }
  blk -= 448;
  if (blk == 0) {                        // bias concat
    if (tid < 128) biasPL[tid] = bpre[tid];
    biasPL[128 + tid] = bloc[tid];
    return;
  }
  blk -= 1;
  // zero d_out: 64 blocks x 256 threads x 4 float4 = 65536 float4 = 262144 floats
  float4 z = {0.f, 0.f, 0.f, 0.f};
#pragma unroll
  for (int i = 0; i < 4; i++)
    ((float4*)outq)[(size_t)blk * 1024 + i * 256 + tid] = z;
}

// ---- K1 + collapsed GCN chain fused ----
// 768 blocks, XCD-swizzled (3 n-siblings/m-tile). n-tile 0: pre-GEMM -> pool
// into LDS -> 3-layer chain (8 samples, per-block local) -> g. n-tiles 1,2:
// loc. A staged from fp32 obs (swizzle invariant kept); B via global_load_lds.
__global__ __launch_bounds__(256, 4) void k1c(
    const float* __restrict__ obs, const bf16* __restrict__ WpreLocT,
    const float* __restrict__ biasPL,
    const bf16* __restrict__ Wg0T, const bf16* __restrict__ Wg1T,
    const bf16* __restrict__ WpostT, const float* __restrict__ b_gcn,
    const float* __restrict__ b_post,
    bf16* __restrict__ loc, bf16* __restrict__ g) {
  __shared__ bf16 smem[16384];
  bf16* As = smem;
  bf16* Bs = smem + 8192;

  const int tid = threadIdx.x;
  const int id = blockIdx.x;
  const int s = id >> 3;
  const int n_idx = s % 3;
  const int m0 = ((id & 7) + 8 * (s / 3)) * 128;
  const int n0 = n_idx * 128;

  f32x4 acc[4][4] = {};
  const int lane = tid & 63, wave = tid >> 6;
  const int wm = (wave >> 1) * 64, wn = (wave & 1) * 64;
  const int lm = lane & 15, quad = lane >> 4;

  for (int k0 = 0; k0 < 128; k0 += 64) {
#pragma unroll
    for (int it = 0; it < 4; it++) {
      int idx = it * 256 + tid;
      int row = idx >> 3;
      int c = idx & 7;
      int cv8 = c ^ (row & 7);
      int kk = k0 + cv8 * 8;
      const float* src = obs + (size_t)(m0 + row) * 128 + kk;
      float4 f0 = *(const float4*)src;
      float4 f1 = *(const float4*)(src + 4);
      bf16x8 v;
      v[0] = (bf16)f0.x; v[1] = (bf16)f0.y; v[2] = (bf16)f0.z; v[3] = (bf16)f0.w;
      v[4] = (bf16)f1.x; v[5] = (bf16)f1.y; v[6] = (bf16)f1.z; v[7] = (bf16)f1.w;
      *(bf16x8*)&As[row * 64 + c * 8] = v;
      const bf16* gb = WpreLocT + (size_t)(n0 + row) * 128 + kk;
      __builtin_amdgcn_global_load_lds(GL(gb), SH(&Bs[(idx & ~63) * 8]), 16, 0, 0);
    }
    __syncthreads();
#pragma unroll
    for (int ks = 0; ks < 2; ks++) {
      const int ua = quad + ks * 4;
      bf16x8 a[4], b[4];
#pragma unroll
      for (int i = 0; i < 4; i++) {
        int r = wm + lm + i * 16;
        a[i] = *(const bf16x8*)&As[r * 64 + ((ua ^ (r & 7)) * 8)];
      }
#pragma unroll
      for (int j = 0; j < 4; j++) {
        int r = wn + lm + j * 16;
        b[j] = *(const bf16x8*)&Bs[r * 64 + ((ua ^ (r & 7)) * 8)];
      }
#pragma unroll
      for (int i = 0; i < 4; i++)
#pragma unroll
        for (int j = 0; j < 4; j++)
          acc[i][j] = MFMA(a[i], b[j], acc[i][j]);
    }
    __syncthreads();
  }

  if (n_idx == 0) {
    // ---- pool into LDS xbar (rows 0..7 real, 8..15 zero) ----
    bf16* xs = smem;            // 16 x 136
    bf16* x2 = smem + 2176;     // 16 x 136
#pragma unroll
    for (int i = 0; i < 4; i++) {
      int sl = (wave >> 1) * 4 + i;     // sample-local 0..7
#pragma unroll
      for (int j = 0; j < 4; j++) {
        int col = wn + j * 16 + lm;
        float bb = biasPL[col];
        float v = 0.f;
#pragma unroll
        for (int r = 0; r < 4; r++) v += fmaxf(acc[i][j][r] + bb, 0.f);
        v += __shfl_xor(v, 16);
        v += __shfl_xor(v, 32);
        if (quad == 0) xs[sl * 136 + col] = (bf16)(v * 0.0625f);
        else if (quad == 1) xs[(8 + sl) * 136 + col] = (bf16)0.f;
      }
    }
    __syncthreads();
    // ---- l0: xs -> x2 ----
    {
      f32x4 c2[2] = {};
#pragma unroll
      for (int ku = 0; ku < 4; ++ku) {
        bf16x8 a = *(const bf16x8*)&xs[lm * 136 + (ku * 4 + quad) * 8];
#pragma unroll
        for (int jn = 0; jn < 2; ++jn) {
          int col = (wave * 2 + jn) * 16 + lm;
          bf16x8 b = *(const bf16x8*)&Wg0T[(size_t)col * 128 + ku * 32 + quad * 8];
          c2[jn] = MFMA(a, b, c2[jn]);
        }
      }
      __syncthreads();
#pragma unroll
      for (int jn = 0; jn < 2; ++jn) {
        int col = (wave * 2 + jn) * 16 + lm;
        float bb = b_gcn[col];
#pragma unroll
        for (int r = 0; r < 4; ++r)
          x2[(quad * 4 + r) * 136 + col] = (bf16)fmaxf(c2[jn][r] + bb, 0.f);
      }
    }
    __syncthreads();
    // ---- l1: x2 -> xs ----
    {
      f32x4 c2[2] = {};
#pragma unroll
      for (int ku = 0; ku < 4; ++ku) {
        bf16x8 a = *(const bf16x8*)&x2[lm * 136 + (ku * 4 + quad) * 8];
#pragma unroll
        for (int jn = 0; jn < 2; ++jn) {
          int col = (wave * 2 + jn) * 16 + lm;
          bf16x8 b = *(const bf16x8*)&Wg1T[(size_t)col * 128 + ku * 32 + quad * 8];
          c2[jn] = MFMA(a, b, c2[jn]);
        }
      }
      __syncthreads();
#pragma unroll
      for (int jn = 0; jn < 2; ++jn) {
        int col = (wave * 2 + jn) * 16 + lm;
        float bb = b_gcn[128 + col];
#pragma unroll
        for (int r = 0; r < 4; ++r)
          xs[(quad * 4 + r) * 136 + col] = (bf16)fmaxf(c2[jn][r] + bb, 0.f);
      }
    }
    __syncthreads();
    // ---- l2: xs -> g (N=256), rows < 8 real ----
    {
      f32x4 c3[4] = {};
#pragma unroll
      for (int ku = 0; ku < 4; ++ku) {
        bf16x8 a = *(const bf16x8*)&xs[lm * 136 + (ku * 4 + quad) * 8];
#pragma unroll
        for (int jn = 0; jn < 4; ++jn) {
          int col = (wave * 4 + jn) * 16 + lm;
          bf16x8 b = *(const bf16x8*)&WpostT[(size_t)col * 128 + ku * 32 + quad * 8];
          c3[jn] = MFMA(a, b, c3[jn]);
        }
      }
      int sample0 = m0 >> 4;
#pragma unroll
      for (int jn = 0; jn < 4; ++jn) {
        int col = (wave * 4 + jn) * 16 + lm;
        float bb = b_post[col];
#pragma unroll
        for (int r = 0; r < 4; ++r) {
          int row = quad * 4 + r;
          if (row < 8)
            g[(size_t)(sample0 + row) * 256 + col] = (bf16)fmaxf(c3[jn][r] + bb, 0.f);
        }
      }
    }
  } else {
    // ---- loc: coalesced store via LDS tile ----
#pragma unroll
    for (int i = 0; i < 4; i++)
#pragma unroll
      for (int j = 0; j < 4; j++) {
        int col = wn + j * 16 + lm;
        float bb = biasPL[n0 + col];
#pragma unroll
        for (int r = 0; r < 4; r++) {
          int row = wm + i * 16 + quad * 4 + r;
          smem[row * 128 + col] = (bf16)fmaxf(acc[i][j][r] + bb, 0.f);
        }
      }
    __syncthreads();
    const int coff = n0 - 128;
#pragma unroll
    for (int c = 0; c < 8; c++) {
      int ci = c * 256 + tid;
      int row = ci >> 4, col8 = (ci & 15) * 8;
      *(bf16x8*)&loc[(size_t)(m0 + row) * 256 + coff + col8] = *(const bf16x8*)&smem[row * 128 + col8];
    }
  }
}

// ---- 128x128 bf16 MFMA GEMM (K3/K4), m97-staged, XCD-swizzled ----
// ASRC: 0 = bf16 [M,512]; 2 = virtual concat [g(rep16) | loc].
// QFUSE: q-head fused, atomic accumulate into out.
template <int ASRC, bool QFUSE>
__global__ __launch_bounds__(256, 4) void gemm_k(
    const bf16* __restrict__ Ab, const bf16* __restrict__ Ag,
    const bf16* __restrict__ BT, const float* __restrict__ bias,
    bf16* __restrict__ C,
    const float* __restrict__ W3, const float* __restrict__ b3,
    float* __restrict__ outq) {
  __shared__ bf16 smem[16384];
  bf16* As = smem;
  bf16* Bs = smem + 8192;

  const int tid = threadIdx.x;
  const int id = blockIdx.x;
  const int s = id >> 3;
  const int n_idx = s & 3;
  const int m0 = ((id & 7) + 8 * (s >> 2)) * 128;
  const int n0 = n_idx * 128;

  f32x4 acc[4][4] = {};
  const int lane = tid & 63, wave = tid >> 6;
  const int wm = (wave >> 1) * 64, wn = (wave & 1) * 64;
  const int lm = lane & 15, quad = lane >> 4;

  for (int k0 = 0; k0 < 512; k0 += 64) {
#pragma unroll
    for (int it = 0; it < 4; it++) {
      int idx = it * 256 + tid;
      int row = idx >> 3;
      int c = idx & 7;
      int cv8 = c ^ (row & 7);
      int kk = k0 + cv8 * 8;
      const bf16* ga;
      if (ASRC == 2) {
        int r = m0 + row;
        ga = (k0 < 256) ? (Ag + (size_t)(r >> 4) * 256 + kk)
                        : (Ab + (size_t)r * 256 + (kk - 256));
      } else {
        ga = Ab + (size_t)(m0 + row) * 512 + kk;
      }
      __builtin_amdgcn_global_load_lds(GL(ga), SH(&As[(idx & ~63) * 8]), 16, 0, 0);
      const bf16* gb = BT + (size_t)(n0 + row) * 512 + kk;
      __builtin_amdgcn_global_load_lds(GL(gb), SH(&Bs[(idx & ~63) * 8]), 16, 0, 0);
    }
    __syncthreads();
#pragma unroll
    for (int ks = 0; ks < 2; ks++) {
      const int ua = quad + ks * 4;
      bf16x8 a[4], b[4];
#pragma unroll
      for (int i = 0; i < 4; i++) {
        int r = wm + lm + i * 16;
        a[i] = *(const bf16x8*)&As[r * 64 + ((ua ^ (r & 7)) * 8)];
      }
#pragma unroll
      for (int j = 0; j < 4; j++) {
        int r = wn + lm + j * 16;
        b[j] = *(const bf16x8*)&Bs[r * 64 + ((ua ^ (r & 7)) * 8)];
      }
#pragma unroll
      for (int i = 0; i < 4; i++)
#pragma unroll
        for (int j = 0; j < 4; j++)
          acc[i][j] = MFMA(a[i], b[j], acc[i][j]);
    }
    __syncthreads();
  }

  if (QFUSE) {
#pragma unroll
    for (int i = 0; i < 4; i++)
#pragma unroll
      for (int j = 0; j < 4; j++) {
        int col = wn + j * 16 + lm;
        float bb = bias[n0 + col];
#pragma unroll
        for (int r = 0; r < 4; r++) {
          int row = wm + i * 16 + quad * 4 + r;
          smem[row * 128 + col] = (bf16)fmaxf(acc[i][j][r] + bb, 0.f);
        }
      }
    __syncthreads();
    int n = lane & 7;
    int kg = lane >> 3;
    float w3r[16];
#pragma unroll
    for (int i = 0; i < 16; i++) w3r[i] = W3[(size_t)(n0 + kg * 16 + i) * 8 + n];
    float bn = (n_idx == 0) ? b3[n] : 0.f;
    int rbase = wave * 32;
    for (int rr = 0; rr < 32; rr++) {
      const bf16* zr = &smem[(rbase + rr) * 128 + kg * 16];
      bf16x8 z0 = *(const bf16x8*)zr;
      bf16x8 z1v = *(const bf16x8*)(zr + 8);
      float v = 0.f;
#pragma unroll
      for (int i = 0; i < 8; i++) v += (float)z0[i] * w3r[i];
#pragma unroll
      for (int i = 0; i < 8; i++) v += (float)z1v[i] * w3r[8 + i];
      v += __shfl_down(v, 32);
      v += __shfl_down(v, 16);
      v += __shfl_down(v, 8);
      if (lane < 8) atomicAdd(&outq[(size_t)(m0 + rbase + rr) * 8 + n], v + bn);
    }
  } else {
#pragma unroll
    for (int i = 0; i < 4; i++)
#pragma unroll
      for (int j = 0; j < 4; j++) {
        int col = wn + j * 16 + lm;
        float bb = bias[n0 + col];
#pragma unroll
        for (int r = 0; r < 4; r++) {
          int row = wm + i * 16 + quad * 4 + r;
          smem[row * 128 + col] = (bf16)fmaxf(acc[i][j][r] + bb, 0.f);
        }
      }
    __syncthreads();
#pragma unroll
    for (int c = 0; c < 8; c++) {
      int ci = c * 256 + tid;
      int row = ci >> 4, col8 = (ci & 15) * 8;
      *(bf16x8*)&C[(size_t)(m0 + row) * 512 + n0 + col8] = *(const bf16x8*)&smem[row * 128 + col8];
    }
  }
}

extern "C" void kernel_launch(void* const* d_in, const int* in_sizes, int n_in,
                              void* d_out, int out_size, void* d_ws, size_t ws_size,
                              hipStream_t stream) {
  const float* obs    = (const float*)d_in[0];
  const float* W_pre  = (const float*)d_in[1];
  const float* b_pre  = (const float*)d_in[2];
  const float* W_gcn  = (const float*)d_in[3];
  const float* b_gcn  = (const float*)d_in[4];
  const float* W_post = (const float*)d_in[5];
  const float* b_post = (const float*)d_in[6];
  const float* W_loc  = (const float*)d_in[7];
  const float* b_loc  = (const float*)d_in[8];
  const float* W1     = (const float*)d_in[9];
  const float* b1     = (const float*)d_in[10];
  const float* W2     = (const float*)d_in[11];
  const float* b2     = (const float*)d_in[12];
  const float* W3     = (const float*)d_in[13];
  const float* b3     = (const float*)d_in[14];
  float* out = (float*)d_out;

  char* p = (char*)d_ws;
  auto alloc = [&](size_t bytes) { char* r = p; p += (bytes + 255) & ~(size_t)255; return r; };
  bf16* WpreLocT = (bf16*)alloc(384 * 128 * 2);
  float* biasPL  = (float*)alloc(384 * 4);
  bf16* Wg0T   = (bf16*)alloc(128 * 128 * 2);
  bf16* Wg1T   = (bf16*)alloc(128 * 128 * 2);
  bf16* WpostT = (bf16*)alloc(256 * 128 * 2);
  bf16* W1T    = (bf16*)alloc(512 * 512 * 2);
  bf16* W2T    = (bf16*)alloc(512 * 512 * 2);
  bf16* locB   = (bf16*)alloc((size_t)32768 * 256 * 2);
  bf16* gB     = (bf16*)alloc(2048 * 256 * 2);
  bf16* z1B    = (bf16*)alloc((size_t)32768 * 512 * 2);

  // P: weight prep + bias + d_out zero
  prep_all<<<641, 256, 0, stream>>>(W1, W2, W1T, W2T,
                                    W_pre, W_loc, W_gcn, W_post,
                                    WpreLocT, Wg0T, Wg1T, WpostT,
                                    b_pre, b_loc, biasPL, out);
  // K1+chain: pre(pool->chain->g) + loc
  k1c<<<768, 256, 0, stream>>>(obs, WpreLocT, biasPL,
                               Wg0T, Wg1T, WpostT, b_gcn, b_post,
                               locB, gB);
  // K3: z1 = relu([g | loc] @ W1 + b1)
  gemm_k<2, false><<<1024, 256, 0, stream>>>(locB, gB, W1T, b1, z1B,
                                             nullptr, nullptr, nullptr);
  // K4: z2 = relu(z1 @ W2 + b2) fused q-head, atomic accumulate into out
  gemm_k<0, true><<<1024, 256, 0, stream>>>(z1B, nullptr, W2T, b2, nullptr,
                                            W3, b3, out);
}